// Round 1
// baseline (1740.953 us; speedup 1.0000x reference)
//
#include <hip/hip_runtime.h>
#include <hip/hip_bf16.h>
#include <math.h>

typedef __hip_bfloat16 bf16;

#define NTOK 147456   // 384*384
#define CDIM 192
#define IMG 384
#define NWIN 2304     // 48*48

__device__ __forceinline__ float ldf(const float* p) { return *p; }
__device__ __forceinline__ float ldf(const bf16* p) { return __bfloat162float(*p); }
__device__ __forceinline__ void stf(float* p, float v) { *p = v; }
__device__ __forceinline__ void stf(bf16* p, float v) { *p = __float2bfloat16(v); }

// window-token row m -> original image row (same map for gather at QKV and
// scatter after attention: win[m] = hidden[gather_row(m)] and
// x_final[gather_row(m)] = attn[m]).
__device__ __forceinline__ int gather_row(int m) {
    int gw = m >> 6, t = m & 63;
    int wr = gw / 48, wc = gw - wr * 48;
    int hh = wr * 8 + (t >> 3);
    int ww = wc * 8 + (t & 7);
    int oh = hh + 4; if (oh >= IMG) oh -= IMG;
    int ow = ww + 4; if (ow >= IMG) ow -= IMG;
    return oh * IMG + ow;
}

#define EPI_NONE 0
#define EPI_GELU 1

// C[M,N] = op(A)[M,K] @ W[K,N] (+bias) (+gelu); 64x64 tile, 256 thr, 4x4/thread
template<bool GATHER, int EPI, typename TA, typename TC>
__global__ __launch_bounds__(256)
void gemm64(const TA* __restrict__ A, const float* __restrict__ W,
            const float* __restrict__ bias, TC* __restrict__ C,
            int N, int K)
{
    __shared__ __align__(16) float sA[16][68];
    __shared__ __align__(16) float sB[16][68];
    const int bm = blockIdx.x * 64;
    const int bn = blockIdx.y * 64;
    const int tid = threadIdx.x;
    const int tm = tid >> 4;          // 0..15
    const int tn = tid & 15;          // 0..15
    // A loader: row lm, k-offset lk..lk+3
    const int lm = tid >> 2;
    const int lk = (tid & 3) * 4;
    int arow = bm + lm;
    if (GATHER) arow = gather_row(arow);
    const TA* Aptr = A + (size_t)arow * K + lk;
    // B loader: col lbn, k-offset lbk..lbk+3
    const int lbn = tid & 63;
    const int lbk = (tid >> 6) * 4;
    const float* Wptr = W + bn + lbn;

    float acc[4][4] = {};
    for (int k0 = 0; k0 < K; k0 += 16) {
#pragma unroll
        for (int i = 0; i < 4; ++i)
            sA[lk + i][lm] = ldf(Aptr + k0 + i);
#pragma unroll
        for (int i = 0; i < 4; ++i)
            sB[lbk + i][lbn] = Wptr[(size_t)(k0 + lbk + i) * N];
        __syncthreads();
#pragma unroll
        for (int kk = 0; kk < 16; ++kk) {
            const float4 a4 = *reinterpret_cast<const float4*>(&sA[kk][tm * 4]);
            const float4 b4 = *reinterpret_cast<const float4*>(&sB[kk][tn * 4]);
            const float av[4] = {a4.x, a4.y, a4.z, a4.w};
            const float bv[4] = {b4.x, b4.y, b4.z, b4.w};
#pragma unroll
            for (int i = 0; i < 4; ++i)
#pragma unroll
                for (int j = 0; j < 4; ++j)
                    acc[i][j] = fmaf(av[i], bv[j], acc[i][j]);
        }
        __syncthreads();
    }
#pragma unroll
    for (int i = 0; i < 4; ++i) {
        const int row = bm + tm * 4 + i;
#pragma unroll
        for (int j = 0; j < 4; ++j) {
            const int col = bn + tn * 4 + j;
            float v = acc[i][j];
            if (bias) v += bias[col];
            if (EPI == EPI_GELU) v = 0.5f * v * (1.0f + erff(v * 0.70710678118654752f));
            stf(&C[(size_t)row * N + col], v);
        }
    }
}

// CPB MLP: one block per table row r in [0,225)
__device__ __forceinline__ float cpb_coord(int i) {
    float a = (float)(i - 7) * (8.0f / 7.0f);
    float s = (a > 0.f) ? 1.f : ((a < 0.f) ? -1.f : 0.f);
    return s * log2f(fabsf(a) + 1.0f) * (1.0f / 3.0f);   // /log2(8)
}

__global__ __launch_bounds__(512)
void cpb_mlp(const float* __restrict__ w1, const float* __restrict__ b1,
             const float* __restrict__ w2, float* __restrict__ tab)
{
    const int r = blockIdx.x;         // 0..224
    const int t = threadIdx.x;        // 0..511
    const float x0 = cpb_coord(r / 15);
    const float x1 = cpb_coord(r % 15);
    const float hgt = fmaxf(x0 * w1[t] + x1 * w1[512 + t] + b1[t], 0.0f);
    __shared__ float red[512];
    for (int n = 0; n < 6; ++n) {
        red[t] = hgt * w2[t * 6 + n];
        __syncthreads();
        for (int s = 256; s > 0; s >>= 1) {
            if (t < s) red[t] += red[t + s];
            __syncthreads();
        }
        if (t == 0) tab[r * 6 + n] = red[0];
        __syncthreads();
    }
}

__global__ __launch_bounds__(256)
void rpb_expand(const float* __restrict__ tab, float* __restrict__ rpb)
{
    const int idx = blockIdx.x * 256 + threadIdx.x;   // < 6*64*64
    if (idx >= 6 * 4096) return;
    const int h = idx >> 12;
    const int t = (idx >> 6) & 63;
    const int j = idx & 63;
    const int pr = t >> 3, pc = t & 7, qr = j >> 3, qc = j & 7;
    const int ridx = (pr - qr + 7) * 15 + (pc - qc + 7);
    const float v = tab[ridx * 6 + h];
    rpb[idx] = 16.0f / (1.0f + expf(-v));
}

// one wave per (window, head): cosine attention + bias + mask + softmax + PV
__global__ __launch_bounds__(64)
void attn64(const float* __restrict__ Q, const float* __restrict__ Km,
            const float* __restrict__ V, const float* __restrict__ rpb,
            const float* __restrict__ logit_scale, float* __restrict__ Ctx)
{
    const int gw = blockIdx.x;    // 0..2303
    const int h  = blockIdx.y;    // 0..5
    const int t  = threadIdx.x;   // 0..63
    __shared__ __align__(16) float kn[64][32];
    __shared__ __align__(16) float vs[64][32];
    __shared__ int rid[64];

    const int wr = gw / 48, wc = gw - wr * 48;
    const int hh = wr * 8 + (t >> 3);
    const int ww = wc * 8 + (t & 7);
    const int rr = (hh < 376) ? 0 : (hh < 380 ? 1 : 2);
    const int rc = (ww < 376) ? 0 : (ww < 380 ? 1 : 2);
    rid[t] = rr * 3 + rc;

    const size_t rowbase = ((size_t)(gw * 64 + t)) * CDIM + h * 32;

    // K row -> normalize -> LDS; V row -> LDS
    {
        float kr[32];
        float nrm = 0.f;
#pragma unroll
        for (int d = 0; d < 32; d += 4) {
            const float4 x = *reinterpret_cast<const float4*>(Km + rowbase + d);
            kr[d] = x.x; kr[d + 1] = x.y; kr[d + 2] = x.z; kr[d + 3] = x.w;
            nrm += x.x * x.x + x.y * x.y + x.z * x.z + x.w * x.w;
        }
        const float rn = 1.0f / fmaxf(sqrtf(nrm), 1e-12f);
#pragma unroll
        for (int d = 0; d < 32; d += 4) {
            float4 o; o.x = kr[d] * rn; o.y = kr[d + 1] * rn; o.z = kr[d + 2] * rn; o.w = kr[d + 3] * rn;
            *reinterpret_cast<float4*>(&kn[t][d]) = o;
        }
#pragma unroll
        for (int d = 0; d < 32; d += 4)
            *reinterpret_cast<float4*>(&vs[t][d]) = *reinterpret_cast<const float4*>(V + rowbase + d);
    }
    __syncthreads();

    // Q row normalize (in regs)
    float qr[32];
    {
        float nrm = 0.f;
#pragma unroll
        for (int d = 0; d < 32; d += 4) {
            const float4 x = *reinterpret_cast<const float4*>(Q + rowbase + d);
            qr[d] = x.x; qr[d + 1] = x.y; qr[d + 2] = x.z; qr[d + 3] = x.w;
            nrm += x.x * x.x + x.y * x.y + x.z * x.z + x.w * x.w;
        }
        const float rn = 1.0f / fmaxf(sqrtf(nrm), 1e-12f);
#pragma unroll
        for (int d = 0; d < 32; ++d) qr[d] *= rn;
    }

    const float scale = expf(fminf(logit_scale[h], 4.6051701859880914f)); // ln(100)
    const float* rpbrow = rpb + ((h * 64 + t) * 64);
    const int myrid = rid[t];

    float sc[64];
    float mx = -1e30f;
#pragma unroll
    for (int j = 0; j < 64; ++j) {
        float dot = 0.f;
#pragma unroll
        for (int d = 0; d < 32; d += 4) {
            const float4 k4 = *reinterpret_cast<const float4*>(&kn[j][d]);
            dot += qr[d] * k4.x + qr[d + 1] * k4.y + qr[d + 2] * k4.z + qr[d + 3] * k4.w;
        }
        float s = dot * scale + rpbrow[j];
        s += (rid[j] == myrid) ? 0.0f : -200.0f;   // reference adds mask twice
        sc[j] = s;
        mx = fmaxf(mx, s);
    }
    float sum = 0.f;
#pragma unroll
    for (int j = 0; j < 64; ++j) {
        const float e = expf(sc[j] - mx);
        sc[j] = e;
        sum += e;
    }
    const float inv = 1.0f / sum;

    float acc[32] = {};
#pragma unroll
    for (int j = 0; j < 64; ++j) {
        const float p = sc[j] * inv;
#pragma unroll
        for (int d = 0; d < 32; d += 4) {
            const float4 v4 = *reinterpret_cast<const float4*>(&vs[j][d]);
            acc[d] += p * v4.x; acc[d + 1] += p * v4.y;
            acc[d + 2] += p * v4.z; acc[d + 3] += p * v4.w;
        }
    }
    // in-place over Q is safe: this thread is the only reader/writer of these addrs
#pragma unroll
    for (int d = 0; d < 32; d += 4) {
        float4 o; o.x = acc[d]; o.y = acc[d + 1]; o.z = acc[d + 2]; o.w = acc[d + 3];
        *reinterpret_cast<float4*>(Ctx + rowbase + d) = o;
    }
}

// Out[orow] = R[orow] + LN(X[tok]) * g + b ; one wave per token
template<bool SCATTER>
__global__ __launch_bounds__(256)
void ln_add(const float* __restrict__ X, const float* __restrict__ R,
            const float* __restrict__ g, const float* __restrict__ b,
            float* __restrict__ Out)
{
    const int lane = threadIdx.x & 63;
    const int tok = blockIdx.x * 4 + (threadIdx.x >> 6);
    const int orow = SCATTER ? gather_row(tok) : tok;
    const float* xr = X + (size_t)tok * CDIM;
    const float x0 = xr[lane], x1 = xr[lane + 64], x2 = xr[lane + 128];
    float s = x0 + x1 + x2;
#pragma unroll
    for (int o = 32; o > 0; o >>= 1) s += __shfl_xor(s, o);
    const float mean = s * (1.0f / 192.0f);
    const float d0 = x0 - mean, d1 = x1 - mean, d2 = x2 - mean;
    float vs = d0 * d0 + d1 * d1 + d2 * d2;
#pragma unroll
    for (int o = 32; o > 0; o >>= 1) vs += __shfl_xor(vs, o);
    const float rstd = rsqrtf(vs * (1.0f / 192.0f) + 1e-5f);
    const float* rr = R + (size_t)orow * CDIM;
    float* op = Out + (size_t)orow * CDIM;
    op[lane]       = rr[lane]       + d0 * rstd * g[lane]       + b[lane];
    op[lane + 64]  = rr[lane + 64]  + d1 * rstd * g[lane + 64]  + b[lane + 64];
    op[lane + 128] = rr[lane + 128] + d2 * rstd * g[lane + 128] + b[lane + 128];
}

extern "C" void kernel_launch(void* const* d_in, const int* in_sizes, int n_in,
                              void* d_out, int out_size, void* d_ws, size_t ws_size,
                              hipStream_t stream)
{
    const float* hidden = (const float*)d_in[0];
    const float* q_w = (const float*)d_in[1];
    const float* q_b = (const float*)d_in[2];
    const float* k_w = (const float*)d_in[3];
    const float* v_w = (const float*)d_in[4];
    const float* v_b = (const float*)d_in[5];
    const float* logit_scale = (const float*)d_in[6];
    const float* cpb_w1 = (const float*)d_in[7];
    const float* cpb_b1 = (const float*)d_in[8];
    const float* cpb_w2 = (const float*)d_in[9];
    const float* proj_w = (const float*)d_in[10];
    const float* proj_b = (const float*)d_in[11];
    const float* ln1_g = (const float*)d_in[12];
    const float* ln1_b = (const float*)d_in[13];
    const float* fc1_w = (const float*)d_in[14];
    const float* fc1_b = (const float*)d_in[15];
    const float* fc2_w = (const float*)d_in[16];
    const float* fc2_b = (const float*)d_in[17];
    const float* ln2_g = (const float*)d_in[18];
    const float* ln2_b = (const float*)d_in[19];

    const size_t S1 = (size_t)NTOK * CDIM * 4;   // 113,246,208 B
    char* ws = (char*)d_ws;
    float* Qb  = (float*)ws;            // q -> ctx (in-place) -> mid(bf16)
    float* Kb  = (float*)(ws + S1);     // k -> x (proj out) -> y (fc2 out)
    float* Vb  = (float*)(ws + 2 * S1); // v -> h
    float* RPB = (float*)(ws + 3 * S1); // 6*4096 floats
    float* TAB = RPB + 6 * 4096;        // 225*6 floats
    float* CTX = Qb;
    float* Xb  = Kb;
    float* Hb  = Vb;
    bf16*  MID = (bf16*)ws;             // NTOK*384 bf16 == S1 bytes
    float* Yb  = Kb;
    float* OUT = (float*)d_out;

    cpb_mlp<<<225, 512, 0, stream>>>(cpb_w1, cpb_b1, cpb_w2, TAB);
    rpb_expand<<<96, 256, 0, stream>>>(TAB, RPB);

    gemm64<true,  EPI_NONE, float, float><<<dim3(NWIN, 3), 256, 0, stream>>>(hidden, q_w, q_b,     Qb, 192, 192);
    gemm64<true,  EPI_NONE, float, float><<<dim3(NWIN, 3), 256, 0, stream>>>(hidden, k_w, nullptr, Kb, 192, 192);
    gemm64<true,  EPI_NONE, float, float><<<dim3(NWIN, 3), 256, 0, stream>>>(hidden, v_w, v_b,     Vb, 192, 192);

    attn64<<<dim3(NWIN, 6), 64, 0, stream>>>(Qb, Kb, Vb, RPB, logit_scale, CTX);

    gemm64<false, EPI_NONE, float, float><<<dim3(NWIN, 3), 256, 0, stream>>>(CTX, proj_w, proj_b, Xb, 192, 192);
    ln_add<true><<<NTOK / 4, 256, 0, stream>>>(Xb, hidden, ln1_g, ln1_b, Hb);

    gemm64<false, EPI_GELU, float, bf16 ><<<dim3(NWIN, 6), 256, 0, stream>>>(Hb, fc1_w, fc1_b, MID, 384, 192);
    gemm64<false, EPI_NONE, bf16,  float><<<dim3(NWIN, 3), 256, 0, stream>>>(MID, fc2_w, fc2_b, Yb, 192, 384);
    ln_add<false><<<NTOK / 4, 256, 0, stream>>>(Yb, Hb, ln2_g, ln2_b, OUT);
}

// Round 2
// 1087.061 us; speedup vs baseline: 1.6015x; 1.6015x over previous
//
#include <hip/hip_runtime.h>
#include <hip/hip_bf16.h>
#include <math.h>

typedef __hip_bfloat16 bf16;
typedef __attribute__((ext_vector_type(8))) short short8;
typedef __attribute__((ext_vector_type(4))) float floatx4;

#define NTOK 147456
#define IMG 384

__device__ __forceinline__ int gather_row(int m) {
    int gw = m >> 6, t = m & 63;
    int wr = gw / 48, wc = gw - wr * 48;
    int hh = wr * 8 + (t >> 3);
    int ww = wc * 8 + (t & 7);
    int oh = hh + 4; if (oh >= IMG) oh -= IMG;
    int ow = ww + 4; if (ow >= IMG) ow -= IMG;
    return oh * IMG + ow;
}

__device__ __forceinline__ unsigned short f2bu(float f) {
    unsigned u = __float_as_uint(f);
    unsigned r = (u + 0x7fffu + ((u >> 16) & 1u)) >> 16;   // RNE
    return (unsigned short)r;
}
__device__ __forceinline__ float bu2f(unsigned short u) {
    return __uint_as_float(((unsigned)u) << 16);
}

// ---------------- prep kernels ----------------

// hidden fp32 -> bf16 A-frag-packed, gathered window order: [mtG][kg24][m16][8]
__global__ __launch_bounds__(256)
void conv_pack(const float* __restrict__ hidden, bf16* __restrict__ Apk)
{
    const int cid = blockIdx.x * 256 + threadIdx.x;    // < 9216*24*16
    const int mtG = cid / 384;
    const int rest = cid - mtG * 384;
    const int kg = rest >> 4, mm = rest & 15;
    const int tok = mtG * 16 + mm;
    const float* p = hidden + (size_t)gather_row(tok) * 192 + kg * 8;
    const float4 a = *(const float4*)p;
    const float4 b = *(const float4*)(p + 4);
    short8 o;
    o[0] = (short)f2bu(a.x); o[1] = (short)f2bu(a.y);
    o[2] = (short)f2bu(a.z); o[3] = (short)f2bu(a.w);
    o[4] = (short)f2bu(b.x); o[5] = (short)f2bu(b.y);
    o[6] = (short)f2bu(b.z); o[7] = (short)f2bu(b.w);
    *(short8*)(Apk + (size_t)cid * 8) = o;
}

// W fp32 [K][N] row-major -> bf16 B-frag-packed [ntG][kg][n16][8]
__global__ __launch_bounds__(256)
void pack_w(const float* __restrict__ W, bf16* __restrict__ out, int K, int N)
{
    const int cid = blockIdx.x * 256 + threadIdx.x;
    const int KG = K >> 3;
    const int total = (N >> 4) * KG * 16;
    if (cid >= total) return;
    const int n = cid & 15;
    const int kg = (cid >> 4) % KG;
    const int ntG = (cid >> 4) / KG;
    short8 o;
#pragma unroll
    for (int j = 0; j < 8; ++j)
        o[j] = (short)f2bu(W[(size_t)(kg * 8 + j) * N + ntG * 16 + n]);
    *(short8*)(out + (size_t)cid * 8) = o;
}

__global__ __launch_bounds__(256)
void fuse_bias(const float* __restrict__ qb, const float* __restrict__ vb,
               float* __restrict__ out)
{
    const int t = blockIdx.x * 256 + threadIdx.x;
    if (t >= 576) return;
    out[t] = (t < 192) ? qb[t] : ((t < 384) ? 0.0f : vb[t - 384]);
}

// ---------------- MFMA GEMM ----------------
// C[M,N] = Apk[M,KDIM] @ Bpk[KDIM,N] (+bias)(+gelu)
// block: 256 thr / 4 waves; BM=128 (wave w: rows w*32..w*32+31); n processed
// in 64-col passes; NPR passes held resident in acc (for K-chunked fc2).
#define EPI_NONE 0
#define EPI_GELU 1

template<int KDIM, int NPR, bool PACK_OUT, int EPI, int KGOUT>
__global__ __launch_bounds__(256, 2)
void gemm_mfma(const bf16* __restrict__ Apk, const bf16* __restrict__ Bpk,
               const float* __restrict__ bias, bf16* __restrict__ C, int N)
{
    constexpr int KG = KDIM / 8;      // total k-groups
    constexpr int KC = KDIM / 192;    // k-chunks of 192
    __shared__ __align__(16) char sA[8 * 24 * 256];   // 49152 B
    __shared__ __align__(16) char sB[4 * 24 * 256];   // 24576 B
    const int tid = threadIdx.x;
    const int wave = tid >> 6, lane = tid & 63;
    const int bm = blockIdx.x * 128;
    const int NPo = N / (64 * NPR);
    const char* Asrc = (const char*)Apk;
    const char* Bsrc = (const char*)Bpk;

    for (int npo = 0; npo < NPo; ++npo) {
        floatx4 acc[NPR][8];
#pragma unroll
        for (int p = 0; p < NPR; ++p)
#pragma unroll
            for (int f = 0; f < 8; ++f)
                acc[p][f] = (floatx4){0.f, 0.f, 0.f, 0.f};

        for (int kc = 0; kc < KC; ++kc) {
            if (KC > 1 || npo == 0) {
                __syncthreads();
#pragma unroll
                for (int i = 0; i < 12; ++i) {        // 3072 chunks of 16B
                    const int cid = tid + (i << 8);
                    const int mtl = cid / 384, off = cid - mtl * 384;
                    const size_t src = ((size_t)((bm >> 4) + mtl) * KG + kc * 24) * 256 + (size_t)off * 16;
                    *(short8*)(sA + mtl * 6144 + off * 16) = *(const short8*)(Asrc + src);
                }
            }
            for (int npi = 0; npi < NPR; ++npi) {
                const int np = npo * NPR + npi;
                __syncthreads();
#pragma unroll
                for (int i = 0; i < 6; ++i) {         // 1536 chunks of 16B
                    const int cid = tid + (i << 8);
                    const int nt = cid / 384, off = cid - nt * 384;
                    const size_t src = ((size_t)(np * 4 + nt) * KG + kc * 24) * 256 + (size_t)off * 16;
                    *(short8*)(sB + nt * 6144 + off * 16) = *(const short8*)(Bsrc + src);
                }
                __syncthreads();
#pragma unroll
                for (int kt = 0; kt < 6; ++kt) {
                    const short8 a0 = *(const short8*)(sA + (wave * 2 + 0) * 6144 + kt * 1024 + lane * 16);
                    const short8 a1 = *(const short8*)(sA + (wave * 2 + 1) * 6144 + kt * 1024 + lane * 16);
#pragma unroll
                    for (int nt = 0; nt < 4; ++nt) {
                        const short8 b = *(const short8*)(sB + nt * 6144 + kt * 1024 + lane * 16);
                        acc[npi][nt]     = __builtin_amdgcn_mfma_f32_16x16x32_bf16(a0, b, acc[npi][nt], 0, 0, 0);
                        acc[npi][4 + nt] = __builtin_amdgcn_mfma_f32_16x16x32_bf16(a1, b, acc[npi][4 + nt], 0, 0, 0);
                    }
                }
            }
        }
        // epilogue: acc -> LDS bounce (bf16, +bias/+gelu) -> 16B stores
        for (int npi = 0; npi < NPR; ++npi) {
            const int np = npo * NPR + npi;
            __syncthreads();                           // all waves done with sB
            char* wb = sB + wave * 4608;               // 32 rows x 72 bf16
#pragma unroll
            for (int m2 = 0; m2 < 2; ++m2) {
#pragma unroll
                for (int nt = 0; nt < 4; ++nt) {
                    const floatx4 v = acc[npi][m2 * 4 + nt];
                    const int c = nt * 16 + (lane & 15);
                    const float bval = bias ? bias[np * 64 + c] : 0.0f;
#pragma unroll
                    for (int i = 0; i < 4; ++i) {
                        float f = v[i] + bval;
                        if (EPI == EPI_GELU)
                            f = 0.5f * f * (1.0f + erff(f * 0.70710678118654752f));
                        const int r = m2 * 16 + (lane >> 4) * 4 + i;
                        *(unsigned short*)(wb + (r * 72 + c) * 2) = f2bu(f);
                    }
                }
            }
            __syncthreads();
            const int m = lane >> 1, coff = (lane & 1) * 32;
            const int grow = bm + wave * 32 + m;
#pragma unroll
            for (int i = 0; i < 4; ++i) {
                const short8 row = *(const short8*)(wb + (m * 72 + coff + i * 8) * 2);
                const int gcol = np * 64 + coff + i * 8;
                bf16* dst;
                if (PACK_OUT)
                    dst = C + ((size_t)((grow >> 4) * KGOUT + (gcol >> 3)) * 16 + (grow & 15)) * 8;
                else
                    dst = C + (size_t)grow * N + gcol;
                *(short8*)dst = row;
            }
        }
    }
}

// ---------------- CPB MLP + RPB ----------------

__device__ __forceinline__ float cpb_coord(int i) {
    float a = (float)(i - 7) * (8.0f / 7.0f);
    float s = (a > 0.f) ? 1.f : ((a < 0.f) ? -1.f : 0.f);
    return s * log2f(fabsf(a) + 1.0f) * (1.0f / 3.0f);
}

__global__ __launch_bounds__(512)
void cpb_mlp(const float* __restrict__ w1, const float* __restrict__ b1,
             const float* __restrict__ w2, float* __restrict__ tab)
{
    const int r = blockIdx.x;
    const int t = threadIdx.x;
    const float x0 = cpb_coord(r / 15);
    const float x1 = cpb_coord(r % 15);
    const float hgt = fmaxf(x0 * w1[t] + x1 * w1[512 + t] + b1[t], 0.0f);
    __shared__ float red[512];
    for (int n = 0; n < 6; ++n) {
        red[t] = hgt * w2[t * 6 + n];
        __syncthreads();
        for (int s = 256; s > 0; s >>= 1) {
            if (t < s) red[t] += red[t + s];
            __syncthreads();
        }
        if (t == 0) tab[r * 6 + n] = red[0];
        __syncthreads();
    }
}

__global__ __launch_bounds__(256)
void rpb_expand(const float* __restrict__ tab, float* __restrict__ rpb)
{
    const int idx = blockIdx.x * 256 + threadIdx.x;
    if (idx >= 6 * 4096) return;
    const int h = idx >> 12;
    const int t = (idx >> 6) & 63;
    const int j = idx & 63;
    const int pr = t >> 3, pc = t & 7, qr = j >> 3, qc = j & 7;
    const int ridx = (pr - qr + 7) * 15 + (pc - qc + 7);
    const float v = tab[ridx * 6 + h];
    rpb[idx] = 16.0f / (1.0f + expf(-v));
}

// ---------------- attention (vector fp32, bf16 IO) ----------------
// one wave per (window, head); QKV fused rows [tok][576]; ctx out packed.
__global__ __launch_bounds__(64)
void attn64(const bf16* __restrict__ QKV, const float* __restrict__ rpb,
            const float* __restrict__ logit_scale, bf16* __restrict__ Ctx)
{
    const int gw = blockIdx.x;
    const int h  = blockIdx.y;
    const int t  = threadIdx.x;
    __shared__ __align__(16) float kn[64][32];
    __shared__ __align__(16) float vs[64][32];
    __shared__ int rid[64];

    const int wr = gw / 48, wc = gw - wr * 48;
    const int hh = wr * 8 + (t >> 3);
    const int ww = wc * 8 + (t & 7);
    const int rr = (hh < 376) ? 0 : (hh < 380 ? 1 : 2);
    const int rc = (ww < 376) ? 0 : (ww < 380 ? 1 : 2);
    rid[t] = rr * 3 + rc;

    const bf16* base = QKV + (size_t)(gw * 64 + t) * 576;

    {   // K -> normalize -> LDS ; V -> LDS
        float kr[32], nrm = 0.f;
#pragma unroll
        for (int c = 0; c < 4; ++c) {
            const short8 raw = *(const short8*)(base + 192 + h * 32 + c * 8);
#pragma unroll
            for (int j = 0; j < 8; ++j) {
                const float f = bu2f((unsigned short)raw[j]);
                kr[c * 8 + j] = f; nrm += f * f;
            }
        }
        const float rn = 1.0f / fmaxf(sqrtf(nrm), 1e-12f);
#pragma unroll
        for (int d = 0; d < 32; ++d) kn[t][d] = kr[d] * rn;
#pragma unroll
        for (int c = 0; c < 4; ++c) {
            const short8 raw = *(const short8*)(base + 384 + h * 32 + c * 8);
#pragma unroll
            for (int j = 0; j < 8; ++j) vs[t][c * 8 + j] = bu2f((unsigned short)raw[j]);
        }
    }
    __syncthreads();

    float qr[32];
    {
        float nrm = 0.f;
#pragma unroll
        for (int c = 0; c < 4; ++c) {
            const short8 raw = *(const short8*)(base + h * 32 + c * 8);
#pragma unroll
            for (int j = 0; j < 8; ++j) {
                const float f = bu2f((unsigned short)raw[j]);
                qr[c * 8 + j] = f; nrm += f * f;
            }
        }
        const float rn = 1.0f / fmaxf(sqrtf(nrm), 1e-12f);
#pragma unroll
        for (int d = 0; d < 32; ++d) qr[d] *= rn;
    }

    const float scale = expf(fminf(logit_scale[h], 4.6051701859880914f));
    const float* rpbrow = rpb + ((h * 64 + t) * 64);
    const int myrid = rid[t];

    float sc[64], mx = -1e30f;
#pragma unroll
    for (int j = 0; j < 64; ++j) {
        float dot = 0.f;
#pragma unroll
        for (int d = 0; d < 32; d += 4) {
            const float4 k4 = *reinterpret_cast<const float4*>(&kn[j][d]);
            dot += qr[d] * k4.x + qr[d + 1] * k4.y + qr[d + 2] * k4.z + qr[d + 3] * k4.w;
        }
        float s = dot * scale + rpbrow[j];
        s += (rid[j] == myrid) ? 0.0f : -200.0f;   // mask added twice in ref
        sc[j] = s;
        mx = fmaxf(mx, s);
    }
    float sum = 0.f;
#pragma unroll
    for (int j = 0; j < 64; ++j) { const float e = expf(sc[j] - mx); sc[j] = e; sum += e; }
    const float inv = 1.0f / sum;

    float acc[32] = {};
#pragma unroll
    for (int j = 0; j < 64; ++j) {
        const float p = sc[j] * inv;
#pragma unroll
        for (int d = 0; d < 32; d += 4) {
            const float4 v4 = *reinterpret_cast<const float4*>(&vs[j][d]);
            acc[d] += p * v4.x; acc[d + 1] += p * v4.y;
            acc[d + 2] += p * v4.z; acc[d + 3] += p * v4.w;
        }
    }
    const int tok = gw * 64 + t, mtG = tok >> 4, mm = tok & 15;
#pragma unroll
    for (int c = 0; c < 4; ++c) {
        const int kg = h * 4 + c;
        short8 o;
#pragma unroll
        for (int j = 0; j < 8; ++j) o[j] = (short)f2bu(acc[c * 8 + j]);
        *(short8*)(Ctx + ((size_t)(mtG * 24 + kg) * 16 + mm) * 8) = o;
    }
}

// ---------------- LN kernels ----------------

// Hres[tok]=h (bf16, window order), Hpk = packed bf16 h ; h = hidden[grow] + LN(X[tok])
__global__ __launch_bounds__(256)
void ln_h(const bf16* __restrict__ X, const float* __restrict__ hidden,
          const float* __restrict__ g, const float* __restrict__ b,
          bf16* __restrict__ Hres, bf16* __restrict__ Hpk)
{
    const int lane = threadIdx.x & 63;
    const int wv = threadIdx.x >> 6;
    const int tok = blockIdx.x * 4 + wv;
    const int grow = gather_row(tok);
    __shared__ float rows[4][192];
    const bf16* xr = X + (size_t)tok * 192;
    const float x0 = bu2f(*(const unsigned short*)(xr + lane));
    const float x1 = bu2f(*(const unsigned short*)(xr + lane + 64));
    const float x2 = bu2f(*(const unsigned short*)(xr + lane + 128));
    float s = x0 + x1 + x2;
#pragma unroll
    for (int o = 32; o > 0; o >>= 1) s += __shfl_xor(s, o);
    const float mean = s * (1.0f / 192.0f);
    const float d0 = x0 - mean, d1 = x1 - mean, d2 = x2 - mean;
    float vsum = d0 * d0 + d1 * d1 + d2 * d2;
#pragma unroll
    for (int o = 32; o > 0; o >>= 1) vsum += __shfl_xor(vsum, o);
    const float rstd = rsqrtf(vsum * (1.0f / 192.0f) + 1e-5f);
    const float* hr = hidden + (size_t)grow * 192;
    const float h0 = hr[lane]       + d0 * rstd * g[lane]       + b[lane];
    const float h1 = hr[lane + 64]  + d1 * rstd * g[lane + 64]  + b[lane + 64];
    const float h2 = hr[lane + 128] + d2 * rstd * g[lane + 128] + b[lane + 128];
    bf16* hres = Hres + (size_t)tok * 192;
    *(unsigned short*)(hres + lane)       = f2bu(h0);
    *(unsigned short*)(hres + lane + 64)  = f2bu(h1);
    *(unsigned short*)(hres + lane + 128) = f2bu(h2);
    rows[wv][lane] = h0; rows[wv][lane + 64] = h1; rows[wv][lane + 128] = h2;
    __syncthreads();
    if (lane < 24) {
        short8 o;
#pragma unroll
        for (int j = 0; j < 8; ++j) o[j] = (short)f2bu(rows[wv][lane * 8 + j]);
        const int mtG = tok >> 4, mm = tok & 15;
        *(short8*)(Hpk + ((size_t)(mtG * 24 + lane) * 16 + mm) * 8) = o;
    }
}

// out[grow] = Hres[tok] + LN(Y[tok]) (fp32)
__global__ __launch_bounds__(256)
void ln_out(const bf16* __restrict__ Y, const bf16* __restrict__ Hres,
            const float* __restrict__ g, const float* __restrict__ b,
            float* __restrict__ Out)
{
    const int lane = threadIdx.x & 63;
    const int tok = blockIdx.x * 4 + (threadIdx.x >> 6);
    const int grow = gather_row(tok);
    const bf16* yr = Y + (size_t)tok * 192;
    const float x0 = bu2f(*(const unsigned short*)(yr + lane));
    const float x1 = bu2f(*(const unsigned short*)(yr + lane + 64));
    const float x2 = bu2f(*(const unsigned short*)(yr + lane + 128));
    float s = x0 + x1 + x2;
#pragma unroll
    for (int o = 32; o > 0; o >>= 1) s += __shfl_xor(s, o);
    const float mean = s * (1.0f / 192.0f);
    const float d0 = x0 - mean, d1 = x1 - mean, d2 = x2 - mean;
    float vsum = d0 * d0 + d1 * d1 + d2 * d2;
#pragma unroll
    for (int o = 32; o > 0; o >>= 1) vsum += __shfl_xor(vsum, o);
    const float rstd = rsqrtf(vsum * (1.0f / 192.0f) + 1e-5f);
    const bf16* hr = Hres + (size_t)tok * 192;
    float* op = Out + (size_t)grow * 192;
    op[lane]       = bu2f(*(const unsigned short*)(hr + lane))       + d0 * rstd * g[lane]       + b[lane];
    op[lane + 64]  = bu2f(*(const unsigned short*)(hr + lane + 64))  + d1 * rstd * g[lane + 64]  + b[lane + 64];
    op[lane + 128] = bu2f(*(const unsigned short*)(hr + lane + 128)) + d2 * rstd * g[lane + 128] + b[lane + 128];
}

// ---------------- launch ----------------

extern "C" void kernel_launch(void* const* d_in, const int* in_sizes, int n_in,
                              void* d_out, int out_size, void* d_ws, size_t ws_size,
                              hipStream_t stream)
{
    const float* hidden = (const float*)d_in[0];
    const float* q_w = (const float*)d_in[1];
    const float* q_b = (const float*)d_in[2];
    const float* k_w = (const float*)d_in[3];
    const float* v_w = (const float*)d_in[4];
    const float* v_b = (const float*)d_in[5];
    const float* logit_scale = (const float*)d_in[6];
    const float* cpb_w1 = (const float*)d_in[7];
    const float* cpb_b1 = (const float*)d_in[8];
    const float* cpb_w2 = (const float*)d_in[9];
    const float* proj_w = (const float*)d_in[10];
    const float* proj_b = (const float*)d_in[11];
    const float* ln1_g = (const float*)d_in[12];
    const float* ln1_b = (const float*)d_in[13];
    const float* fc1_w = (const float*)d_in[14];
    const float* fc1_b = (const float*)d_in[15];
    const float* fc2_w = (const float*)d_in[16];
    const float* fc2_b = (const float*)d_in[17];
    const float* ln2_g = (const float*)d_in[18];
    const float* ln2_b = (const float*)d_in[19];

    char* ws = (char*)d_ws;
    // workspace map (bytes) — total 339,738,624 (== 3 * NTOK*192*4, proven in R0)
    bf16*  APK   = (bf16*)(ws + 0);                    // [0, 56.6M)  t0-t1
    float* RPB   = (float*)(ws + 0);                   // after QKV gemm
    bf16*  PROJW = (bf16*)(ws + (1 << 20));            // after QKV gemm
    bf16*  MID   = (bf16*)(ws + 0);                    // [0, 113.2M) fc1 out
    bf16*  CTX   = (bf16*)(ws + 56623104);             // attn out (t2-t3)
    bf16*  QKVW  = (bf16*)(ws + 56623104);             // pre-QKV only
    float* QKVB  = (float*)(ws + 56844288);
    float* TAB   = (float*)(ws + 56846592);
    bf16*  QKV   = (bf16*)(ws + 113246208);            // [113.2M, 283.1M) t1-t2
    bf16*  HRES  = (bf16*)(ws + 113246208);            // after attn
    bf16*  HPK   = (bf16*)(ws + 169869312);
    bf16*  Y     = (bf16*)(ws + 226492416);
    bf16*  X     = (bf16*)(ws + 283115520);            // [283.1M, 339.7M) t3-t4
    bf16*  FC1W  = (bf16*)(ws + 283115520);            // after ln1
    bf16*  FC2W  = (bf16*)(ws + 283262976);
    float* OUT   = (float*)d_out;

    cpb_mlp<<<225, 512, 0, stream>>>(cpb_w1, cpb_b1, cpb_w2, TAB);
    fuse_bias<<<3, 256, 0, stream>>>(q_b, v_b, QKVB);
    pack_w<<<18, 256, 0, stream>>>(q_w, QKVW,                 192, 192);
    pack_w<<<18, 256, 0, stream>>>(k_w, QKVW + 12 * 24 * 128, 192, 192);
    pack_w<<<18, 256, 0, stream>>>(v_w, QKVW + 24 * 24 * 128, 192, 192);
    conv_pack<<<13824, 256, 0, stream>>>(hidden, APK);

    gemm_mfma<192, 1, false, EPI_NONE, 1><<<1152, 256, 0, stream>>>(APK, QKVW, QKVB, QKV, 576);

    rpb_expand<<<96, 256, 0, stream>>>(TAB, RPB);
    pack_w<<<18, 256, 0, stream>>>(proj_w, PROJW, 192, 192);

    attn64<<<dim3(2304, 6), 64, 0, stream>>>(QKV, RPB, logit_scale, CTX);

    gemm_mfma<192, 1, false, EPI_NONE, 1><<<1152, 256, 0, stream>>>(CTX, PROJW, proj_b, X, 192);

    ln_h<<<NTOK / 4, 256, 0, stream>>>(X, hidden, ln1_g, ln1_b, HRES, HPK);

    pack_w<<<36, 256, 0, stream>>>(fc1_w, FC1W, 192, 384);
    pack_w<<<36, 256, 0, stream>>>(fc2_w, FC2W, 384, 192);

    gemm_mfma<192, 1, true, EPI_GELU, 48><<<1152, 256, 0, stream>>>(HPK, FC1W, fc1_b, MID, 384);
    gemm_mfma<384, 3, false, EPI_NONE, 1><<<1152, 256, 0, stream>>>(MID, FC2W, fc2_b, Y, 192);

    ln_out<<<NTOK / 4, 256, 0, stream>>>(Y, HRES, ln2_g, ln2_b, OUT);
}

// Round 3
// 814.697 us; speedup vs baseline: 2.1369x; 1.3343x over previous
//
#include <hip/hip_runtime.h>
#include <hip/hip_bf16.h>
#include <math.h>

typedef __hip_bfloat16 bf16;
typedef __attribute__((ext_vector_type(8))) short short8;
typedef __attribute__((ext_vector_type(4))) float floatx4;

#define NTOK 147456
#define IMG 384

__device__ __forceinline__ int gather_row(int m) {
    int gw = m >> 6, t = m & 63;
    int wr = gw / 48, wc = gw - wr * 48;
    int hh = wr * 8 + (t >> 3);
    int ww = wc * 8 + (t & 7);
    int oh = hh + 4; if (oh >= IMG) oh -= IMG;
    int ow = ww + 4; if (ow >= IMG) ow -= IMG;
    return oh * IMG + ow;
}

__device__ __forceinline__ unsigned short f2bu(float f) {
    unsigned u = __float_as_uint(f);
    unsigned r = (u + 0x7fffu + ((u >> 16) & 1u)) >> 16;   // RNE
    return (unsigned short)r;
}
__device__ __forceinline__ float bu2f(unsigned short u) {
    return __uint_as_float(((unsigned)u) << 16);
}

// ---------------- prep kernels ----------------

// hidden fp32 -> bf16 A-frag-packed, gathered window order: [mtG][kg24][m16][8]
__global__ __launch_bounds__(256)
void conv_pack(const float* __restrict__ hidden, bf16* __restrict__ Apk)
{
    const int cid = blockIdx.x * 256 + threadIdx.x;    // < 9216*24*16
    const int mtG = cid / 384;
    const int rest = cid - mtG * 384;
    const int kg = rest >> 4, mm = rest & 15;
    const int tok = mtG * 16 + mm;
    const float* p = hidden + (size_t)gather_row(tok) * 192 + kg * 8;
    const float4 a = *(const float4*)p;
    const float4 b = *(const float4*)(p + 4);
    short8 o;
    o[0] = (short)f2bu(a.x); o[1] = (short)f2bu(a.y);
    o[2] = (short)f2bu(a.z); o[3] = (short)f2bu(a.w);
    o[4] = (short)f2bu(b.x); o[5] = (short)f2bu(b.y);
    o[6] = (short)f2bu(b.z); o[7] = (short)f2bu(b.w);
    *(short8*)(Apk + (size_t)cid * 8) = o;
}

// W fp32 [K][N] row-major -> bf16 B-frag-packed [ntG][kg][n16][8]
__global__ __launch_bounds__(256)
void pack_w(const float* __restrict__ W, bf16* __restrict__ out, int K, int N)
{
    const int cid = blockIdx.x * 256 + threadIdx.x;
    const int KG = K >> 3;
    const int total = (N >> 4) * KG * 16;
    if (cid >= total) return;
    const int n = cid & 15;
    const int kg = (cid >> 4) % KG;
    const int ntG = (cid >> 4) / KG;
    short8 o;
#pragma unroll
    for (int j = 0; j < 8; ++j)
        o[j] = (short)f2bu(W[(size_t)(kg * 8 + j) * N + ntG * 16 + n]);
    *(short8*)(out + (size_t)cid * 8) = o;
}

__global__ __launch_bounds__(256)
void fuse_bias(const float* __restrict__ qb, const float* __restrict__ vb,
               float* __restrict__ out)
{
    const int t = blockIdx.x * 256 + threadIdx.x;
    if (t >= 576) return;
    out[t] = (t < 192) ? qb[t] : ((t < 384) ? 0.0f : vb[t - 384]);
}

// ---------------- MFMA GEMM ----------------
#define EPI_NONE 0
#define EPI_GELU 1

template<int KDIM, int NPR, bool PACK_OUT, int EPI, int KGOUT>
__global__ __launch_bounds__(256, 2)
void gemm_mfma(const bf16* __restrict__ Apk, const bf16* __restrict__ Bpk,
               const float* __restrict__ bias, bf16* __restrict__ C, int N)
{
    constexpr int KG = KDIM / 8;
    constexpr int KC = KDIM / 192;
    __shared__ __align__(16) char sA[8 * 24 * 256];
    __shared__ __align__(16) char sB[4 * 24 * 256];
    const int tid = threadIdx.x;
    const int wave = tid >> 6, lane = tid & 63;
    const int bm = blockIdx.x * 128;
    const int NPo = N / (64 * NPR);
    const char* Asrc = (const char*)Apk;
    const char* Bsrc = (const char*)Bpk;

    for (int npo = 0; npo < NPo; ++npo) {
        floatx4 acc[NPR][8];
#pragma unroll
        for (int p = 0; p < NPR; ++p)
#pragma unroll
            for (int f = 0; f < 8; ++f)
                acc[p][f] = (floatx4){0.f, 0.f, 0.f, 0.f};

        for (int kc = 0; kc < KC; ++kc) {
            if (KC > 1 || npo == 0) {
                __syncthreads();
#pragma unroll
                for (int i = 0; i < 12; ++i) {
                    const int cid = tid + (i << 8);
                    const int mtl = cid / 384, off = cid - mtl * 384;
                    const size_t src = ((size_t)((bm >> 4) + mtl) * KG + kc * 24) * 256 + (size_t)off * 16;
                    *(short8*)(sA + mtl * 6144 + off * 16) = *(const short8*)(Asrc + src);
                }
            }
            for (int npi = 0; npi < NPR; ++npi) {
                const int np = npo * NPR + npi;
                __syncthreads();
#pragma unroll
                for (int i = 0; i < 6; ++i) {
                    const int cid = tid + (i << 8);
                    const int nt = cid / 384, off = cid - nt * 384;
                    const size_t src = ((size_t)(np * 4 + nt) * KG + kc * 24) * 256 + (size_t)off * 16;
                    *(short8*)(sB + nt * 6144 + off * 16) = *(const short8*)(Bsrc + src);
                }
                __syncthreads();
#pragma unroll
                for (int kt = 0; kt < 6; ++kt) {
                    const short8 a0 = *(const short8*)(sA + (wave * 2 + 0) * 6144 + kt * 1024 + lane * 16);
                    const short8 a1 = *(const short8*)(sA + (wave * 2 + 1) * 6144 + kt * 1024 + lane * 16);
#pragma unroll
                    for (int nt = 0; nt < 4; ++nt) {
                        const short8 b = *(const short8*)(sB + nt * 6144 + kt * 1024 + lane * 16);
                        acc[npi][nt]     = __builtin_amdgcn_mfma_f32_16x16x32_bf16(a0, b, acc[npi][nt], 0, 0, 0);
                        acc[npi][4 + nt] = __builtin_amdgcn_mfma_f32_16x16x32_bf16(a1, b, acc[npi][4 + nt], 0, 0, 0);
                    }
                }
            }
        }
        for (int npi = 0; npi < NPR; ++npi) {
            const int np = npo * NPR + npi;
            __syncthreads();
            char* wb = sB + wave * 4608;
#pragma unroll
            for (int m2 = 0; m2 < 2; ++m2) {
#pragma unroll
                for (int nt = 0; nt < 4; ++nt) {
                    const floatx4 v = acc[npi][m2 * 4 + nt];
                    const int c = nt * 16 + (lane & 15);
                    const float bval = bias ? bias[np * 64 + c] : 0.0f;
#pragma unroll
                    for (int i = 0; i < 4; ++i) {
                        float f = v[i] + bval;
                        if (EPI == EPI_GELU)
                            f = 0.5f * f * (1.0f + erff(f * 0.70710678118654752f));
                        const int r = m2 * 16 + (lane >> 4) * 4 + i;
                        *(unsigned short*)(wb + (r * 72 + c) * 2) = f2bu(f);
                    }
                }
            }
            __syncthreads();
            const int m = lane >> 1, coff = (lane & 1) * 32;
            const int grow = bm + wave * 32 + m;
#pragma unroll
            for (int i = 0; i < 4; ++i) {
                const short8 row = *(const short8*)(wb + (m * 72 + coff + i * 8) * 2);
                const int gcol = np * 64 + coff + i * 8;
                bf16* dst;
                if (PACK_OUT)
                    dst = C + ((size_t)((grow >> 4) * KGOUT + (gcol >> 3)) * 16 + (grow & 15)) * 8;
                else
                    dst = C + (size_t)grow * N + gcol;
                *(short8*)dst = row;
            }
        }
    }
}

// ---------------- CPB MLP + RPB ----------------

__device__ __forceinline__ float cpb_coord(int i) {
    float a = (float)(i - 7) * (8.0f / 7.0f);
    float s = (a > 0.f) ? 1.f : ((a < 0.f) ? -1.f : 0.f);
    return s * log2f(fabsf(a) + 1.0f) * (1.0f / 3.0f);
}

__global__ __launch_bounds__(512)
void cpb_mlp(const float* __restrict__ w1, const float* __restrict__ b1,
             const float* __restrict__ w2, float* __restrict__ tab)
{
    const int r = blockIdx.x;
    const int t = threadIdx.x;
    const float x0 = cpb_coord(r / 15);
    const float x1 = cpb_coord(r % 15);
    const float hgt = fmaxf(x0 * w1[t] + x1 * w1[512 + t] + b1[t], 0.0f);
    __shared__ float red[512];
    for (int n = 0; n < 6; ++n) {
        red[t] = hgt * w2[t * 6 + n];
        __syncthreads();
        for (int s = 256; s > 0; s >>= 1) {
            if (t < s) red[t] += red[t + s];
            __syncthreads();
        }
        if (t == 0) tab[r * 6 + n] = red[0];
        __syncthreads();
    }
}

__global__ __launch_bounds__(256)
void rpb_expand(const float* __restrict__ tab, float* __restrict__ rpb)
{
    const int idx = blockIdx.x * 256 + threadIdx.x;
    if (idx >= 6 * 4096) return;
    const int h = idx >> 12;
    const int t = (idx >> 6) & 63;
    const int j = idx & 63;
    const int pr = t >> 3, pc = t & 7, qr = j >> 3, qc = j & 7;
    const int ridx = (pr - qr + 7) * 15 + (pc - qc + 7);
    const float v = tab[ridx * 6 + h];
    rpb[idx] = 16.0f / (1.0f + expf(-v));
}

// ---------------- MFMA attention ----------------
// one wave per (window, head); 4 waves/block; all LDS wave-private (no barriers).
// S = Qn Kn^T via 16x16x32 MFMA (frags loaded direct from global),
// softmax in C-layout regs, P -> LDS (two 32-key halves) -> PV MFMA with
// V^T staged in LDS; ctx scaled by 1/sum and emitted in packed-A layout.
__global__ __launch_bounds__(256, 2)
void attn_mfma(const bf16* __restrict__ QKV, const float* __restrict__ rpb,
               const float* __restrict__ logit_scale, bf16* __restrict__ Ctx)
{
    __shared__ __align__(16) char lds[4][9216];
    const int wave = threadIdx.x >> 6, lane = threadIdx.x & 63;
    const int l15 = lane & 15, quad = lane >> 4;
    const int wh = blockIdx.x * 4 + wave;
    const int w = wh / 6, h = wh - w * 6;
    char* Pb = lds[wave];            // 64 rows x 36 bf16 (P halves, then ctx)
    char* Vt = lds[wave] + 4608;     // 32 rows x 72 bf16 (V transposed)

    const bf16* wbase = QKV + (size_t)w * 64 * 576;

    // ---- stage V^T: lane = token, writes its column (2 lanes/bank: free) ----
    {
        const bf16* vp = wbase + (size_t)lane * 576 + 384 + h * 32;
        const short8 v0 = *(const short8*)(vp);
        const short8 v1 = *(const short8*)(vp + 8);
        const short8 v2 = *(const short8*)(vp + 16);
        const short8 v3 = *(const short8*)(vp + 24);
#pragma unroll
        for (int j = 0; j < 8; ++j) {
            *(short*)(Vt + ((j     ) * 72 + lane) * 2) = v0[j];
            *(short*)(Vt + ((j +  8) * 72 + lane) * 2) = v1[j];
            *(short*)(Vt + ((j + 16) * 72 + lane) * 2) = v2[j];
            *(short*)(Vt + ((j + 24) * 72 + lane) * 2) = v3[j];
        }
    }

    // ---- region ids (mask only matters on last window row/col) ----
    const int wr = w / 48, wc = w - wr * 48;
    const bool edge = (wr == 47) || (wc == 47);
    int rid_j[4];
    if (edge) {
#pragma unroll
        for (int jt = 0; jt < 4; ++jt) {
            const int t = jt * 16 + l15;
            const int rr = (wr == 47) ? (((t >> 3) < 4) ? 1 : 2) : 0;
            const int rc = (wc == 47) ? (((t & 7) < 4) ? 1 : 2) : 0;
            rid_j[jt] = rr * 3 + rc;
        }
    }

    // ---- K B-frags, cosine-normalized ----
    short8 bfrag[4];
#pragma unroll
    for (int jt = 0; jt < 4; ++jt) {
        const short8 raw = *(const short8*)(wbase + (size_t)(jt * 16 + l15) * 576 + 192 + h * 32 + quad * 8);
        float f[8]; float ss = 0.f;
#pragma unroll
        for (int j = 0; j < 8; ++j) { f[j] = bu2f((unsigned short)raw[j]); ss += f[j] * f[j]; }
        ss += __shfl_xor(ss, 16); ss += __shfl_xor(ss, 32);
        const float rn = 1.0f / fmaxf(sqrtf(ss), 1e-12f);
        short8 o;
#pragma unroll
        for (int j = 0; j < 8; ++j) o[j] = (short)f2bu(f[j] * rn);
        bfrag[jt] = o;
    }

    // ---- S = Qn Kn^T ----
    floatx4 acc[4][4];
#pragma unroll
    for (int it = 0; it < 4; ++it)
#pragma unroll
        for (int jt = 0; jt < 4; ++jt)
            acc[it][jt] = (floatx4){0.f, 0.f, 0.f, 0.f};
#pragma unroll
    for (int it = 0; it < 4; ++it) {
        const short8 raw = *(const short8*)(wbase + (size_t)(it * 16 + l15) * 576 + h * 32 + quad * 8);
        float f[8]; float ss = 0.f;
#pragma unroll
        for (int j = 0; j < 8; ++j) { f[j] = bu2f((unsigned short)raw[j]); ss += f[j] * f[j]; }
        ss += __shfl_xor(ss, 16); ss += __shfl_xor(ss, 32);
        const float rn = 1.0f / fmaxf(sqrtf(ss), 1e-12f);
        short8 afr;
#pragma unroll
        for (int j = 0; j < 8; ++j) afr[j] = (short)f2bu(f[j] * rn);
#pragma unroll
        for (int jt = 0; jt < 4; ++jt)
            acc[it][jt] = __builtin_amdgcn_mfma_f32_16x16x32_bf16(afr, bfrag[jt], acc[it][jt], 0, 0, 0);
    }

    const float scale = __expf(fminf(logit_scale[h], 4.6051701859880914f));
    const float* rpbh = rpb + h * 4096;

    // ---- scale + bias + mask (C-layout: row = it*16+quad*4+r, col = jt*16+l15) ----
#pragma unroll
    for (int it = 0; it < 4; ++it) {
#pragma unroll
        for (int r = 0; r < 4; ++r) {
            const int i = it * 16 + quad * 4 + r;
            int rid_i = 0;
            if (edge) {
                const int rr = (wr == 47) ? (((i >> 3) < 4) ? 1 : 2) : 0;
                const int rc = (wc == 47) ? (((i & 7) < 4) ? 1 : 2) : 0;
                rid_i = rr * 3 + rc;
            }
#pragma unroll
            for (int jt = 0; jt < 4; ++jt) {
                float v = acc[it][jt][r] * scale + rpbh[i * 64 + jt * 16 + l15];
                if (edge && rid_i != rid_j[jt]) v -= 200.0f;   // mask added twice in ref
                acc[it][jt][r] = v;
            }
        }
    }

    // ---- softmax per row; keep 1/sum for post-PV scaling ----
    float inv[4][4];
#pragma unroll
    for (int it = 0; it < 4; ++it) {
#pragma unroll
        for (int r = 0; r < 4; ++r) {
            float m = fmaxf(fmaxf(acc[it][0][r], acc[it][1][r]),
                            fmaxf(acc[it][2][r], acc[it][3][r]));
            m = fmaxf(m, __shfl_xor(m, 1)); m = fmaxf(m, __shfl_xor(m, 2));
            m = fmaxf(m, __shfl_xor(m, 4)); m = fmaxf(m, __shfl_xor(m, 8));
            float s = 0.f;
#pragma unroll
            for (int jt = 0; jt < 4; ++jt) {
                const float e = __expf(acc[it][jt][r] - m);
                acc[it][jt][r] = e; s += e;
            }
            s += __shfl_xor(s, 1); s += __shfl_xor(s, 2);
            s += __shfl_xor(s, 4); s += __shfl_xor(s, 8);
            inv[it][r] = 1.0f / s;
        }
    }

    // ---- ctx = P V via LDS round-trip in two 32-key halves ----
    floatx4 ctx[4][2];
#pragma unroll
    for (int it = 0; it < 4; ++it)
#pragma unroll
        for (int dt = 0; dt < 2; ++dt)
            ctx[it][dt] = (floatx4){0.f, 0.f, 0.f, 0.f};

#pragma unroll
    for (int ks = 0; ks < 2; ++ks) {
#pragma unroll
        for (int it = 0; it < 4; ++it)
#pragma unroll
            for (int jl = 0; jl < 2; ++jl)
#pragma unroll
                for (int r = 0; r < 4; ++r) {
                    const int i = it * 16 + quad * 4 + r;
                    *(short*)(Pb + (i * 36 + jl * 16 + l15) * 2) =
                        (short)f2bu(acc[it][ks * 2 + jl][r]);
                }
#pragma unroll
        for (int it = 0; it < 4; ++it) {
            const short8 pf = *(const short8*)(Pb + ((it * 16 + l15) * 36 + quad * 8) * 2);
#pragma unroll
            for (int dt = 0; dt < 2; ++dt) {
                const short8 vf = *(const short8*)(Vt + ((dt * 16 + l15) * 72 + ks * 32 + quad * 8) * 2);
                ctx[it][dt] = __builtin_amdgcn_mfma_f32_16x16x32_bf16(pf, vf, ctx[it][dt], 0, 0, 0);
            }
        }
    }

    // ---- ctx/sum -> LDS (reuse Pb; same-wave order keeps it race-free) ----
#pragma unroll
    for (int it = 0; it < 4; ++it)
#pragma unroll
        for (int dt = 0; dt < 2; ++dt)
#pragma unroll
            for (int r = 0; r < 4; ++r) {
                const int i = it * 16 + quad * 4 + r;
                *(short*)(Pb + (i * 36 + dt * 16 + l15) * 2) =
                    (short)f2bu(ctx[it][dt][r] * inv[it][r]);
            }

    // ---- packed-A-layout store for proj GEMM ----
    const int tok = w * 64 + lane;
    const size_t obase = ((size_t)(tok >> 4) * 24 + h * 4) * 128 + (size_t)(tok & 15) * 8;
#pragma unroll
    for (int c = 0; c < 4; ++c) {
        const short8 row = *(const short8*)(Pb + (lane * 36 + c * 8) * 2);
        *(short8*)(Ctx + obase + (size_t)c * 128) = row;
    }
}

// ---------------- LN kernels ----------------

__global__ __launch_bounds__(256)
void ln_h(const bf16* __restrict__ X, const float* __restrict__ hidden,
          const float* __restrict__ g, const float* __restrict__ b,
          bf16* __restrict__ Hres, bf16* __restrict__ Hpk)
{
    const int lane = threadIdx.x & 63;
    const int wv = threadIdx.x >> 6;
    const int tok = blockIdx.x * 4 + wv;
    const int grow = gather_row(tok);
    __shared__ float rows[4][192];
    const bf16* xr = X + (size_t)tok * 192;
    const float x0 = bu2f(*(const unsigned short*)(xr + lane));
    const float x1 = bu2f(*(const unsigned short*)(xr + lane + 64));
    const float x2 = bu2f(*(const unsigned short*)(xr + lane + 128));
    float s = x0 + x1 + x2;
#pragma unroll
    for (int o = 32; o > 0; o >>= 1) s += __shfl_xor(s, o);
    const float mean = s * (1.0f / 192.0f);
    const float d0 = x0 - mean, d1 = x1 - mean, d2 = x2 - mean;
    float vsum = d0 * d0 + d1 * d1 + d2 * d2;
#pragma unroll
    for (int o = 32; o > 0; o >>= 1) vsum += __shfl_xor(vsum, o);
    const float rstd = rsqrtf(vsum * (1.0f / 192.0f) + 1e-5f);
    const float* hr = hidden + (size_t)grow * 192;
    const float h0 = hr[lane]       + d0 * rstd * g[lane]       + b[lane];
    const float h1 = hr[lane + 64]  + d1 * rstd * g[lane + 64]  + b[lane + 64];
    const float h2 = hr[lane + 128] + d2 * rstd * g[lane + 128] + b[lane + 128];
    bf16* hres = Hres + (size_t)tok * 192;
    *(unsigned short*)(hres + lane)       = f2bu(h0);
    *(unsigned short*)(hres + lane + 64)  = f2bu(h1);
    *(unsigned short*)(hres + lane + 128) = f2bu(h2);
    rows[wv][lane] = h0; rows[wv][lane + 64] = h1; rows[wv][lane + 128] = h2;
    __syncthreads();
    if (lane < 24) {
        short8 o;
#pragma unroll
        for (int j = 0; j < 8; ++j) o[j] = (short)f2bu(rows[wv][lane * 8 + j]);
        const int mtG = tok >> 4, mm = tok & 15;
        *(short8*)(Hpk + ((size_t)(mtG * 24 + lane) * 16 + mm) * 8) = o;
    }
}

__global__ __launch_bounds__(256)
void ln_out(const bf16* __restrict__ Y, const bf16* __restrict__ Hres,
            const float* __restrict__ g, const float* __restrict__ b,
            float* __restrict__ Out)
{
    const int lane = threadIdx.x & 63;
    const int tok = blockIdx.x * 4 + (threadIdx.x >> 6);
    const int grow = gather_row(tok);
    const bf16* yr = Y + (size_t)tok * 192;
    const float x0 = bu2f(*(const unsigned short*)(yr + lane));
    const float x1 = bu2f(*(const unsigned short*)(yr + lane + 64));
    const float x2 = bu2f(*(const unsigned short*)(yr + lane + 128));
    float s = x0 + x1 + x2;
#pragma unroll
    for (int o = 32; o > 0; o >>= 1) s += __shfl_xor(s, o);
    const float mean = s * (1.0f / 192.0f);
    const float d0 = x0 - mean, d1 = x1 - mean, d2 = x2 - mean;
    float vsum = d0 * d0 + d1 * d1 + d2 * d2;
#pragma unroll
    for (int o = 32; o > 0; o >>= 1) vsum += __shfl_xor(vsum, o);
    const float rstd = rsqrtf(vsum * (1.0f / 192.0f) + 1e-5f);
    const bf16* hr = Hres + (size_t)tok * 192;
    float* op = Out + (size_t)grow * 192;
    op[lane]       = bu2f(*(const unsigned short*)(hr + lane))       + d0 * rstd * g[lane]       + b[lane];
    op[lane + 64]  = bu2f(*(const unsigned short*)(hr + lane + 64))  + d1 * rstd * g[lane + 64]  + b[lane + 64];
    op[lane + 128] = bu2f(*(const unsigned short*)(hr + lane + 128)) + d2 * rstd * g[lane + 128] + b[lane + 128];
}

// ---------------- launch ----------------

extern "C" void kernel_launch(void* const* d_in, const int* in_sizes, int n_in,
                              void* d_out, int out_size, void* d_ws, size_t ws_size,
                              hipStream_t stream)
{
    const float* hidden = (const float*)d_in[0];
    const float* q_w = (const float*)d_in[1];
    const float* q_b = (const float*)d_in[2];
    const float* k_w = (const float*)d_in[3];
    const float* v_w = (const float*)d_in[4];
    const float* v_b = (const float*)d_in[5];
    const float* logit_scale = (const float*)d_in[6];
    const float* cpb_w1 = (const float*)d_in[7];
    const float* cpb_b1 = (const float*)d_in[8];
    const float* cpb_w2 = (const float*)d_in[9];
    const float* proj_w = (const float*)d_in[10];
    const float* proj_b = (const float*)d_in[11];
    const float* ln1_g = (const float*)d_in[12];
    const float* ln1_b = (const float*)d_in[13];
    const float* fc1_w = (const float*)d_in[14];
    const float* fc1_b = (const float*)d_in[15];
    const float* fc2_w = (const float*)d_in[16];
    const float* fc2_b = (const float*)d_in[17];
    const float* ln2_g = (const float*)d_in[18];
    const float* ln2_b = (const float*)d_in[19];

    char* ws = (char*)d_ws;
    bf16*  APK   = (bf16*)(ws + 0);
    float* RPB   = (float*)(ws + 0);
    bf16*  PROJW = (bf16*)(ws + (1 << 20));
    bf16*  MID   = (bf16*)(ws + 0);
    bf16*  CTX   = (bf16*)(ws + 56623104);
    bf16*  QKVW  = (bf16*)(ws + 56623104);
    float* QKVB  = (float*)(ws + 56844288);
    float* TAB   = (float*)(ws + 56846592);
    bf16*  QKV   = (bf16*)(ws + 113246208);
    bf16*  HRES  = (bf16*)(ws + 113246208);
    bf16*  HPK   = (bf16*)(ws + 169869312);
    bf16*  Y     = (bf16*)(ws + 226492416);
    bf16*  X     = (bf16*)(ws + 283115520);
    bf16*  FC1W  = (bf16*)(ws + 283115520);
    bf16*  FC2W  = (bf16*)(ws + 283262976);
    float* OUT   = (float*)d_out;

    cpb_mlp<<<225, 512, 0, stream>>>(cpb_w1, cpb_b1, cpb_w2, TAB);
    fuse_bias<<<3, 256, 0, stream>>>(q_b, v_b, QKVB);
    pack_w<<<18, 256, 0, stream>>>(q_w, QKVW,                 192, 192);
    pack_w<<<18, 256, 0, stream>>>(k_w, QKVW + 12 * 24 * 128, 192, 192);
    pack_w<<<18, 256, 0, stream>>>(v_w, QKVW + 24 * 24 * 128, 192, 192);
    conv_pack<<<13824, 256, 0, stream>>>(hidden, APK);

    gemm_mfma<192, 1, false, EPI_NONE, 1><<<1152, 256, 0, stream>>>(APK, QKVW, QKVB, QKV, 576);

    rpb_expand<<<96, 256, 0, stream>>>(TAB, RPB);
    pack_w<<<18, 256, 0, stream>>>(proj_w, PROJW, 192, 192);

    attn_mfma<<<3456, 256, 0, stream>>>(QKV, RPB, logit_scale, CTX);

    gemm_mfma<192, 1, false, EPI_NONE, 1><<<1152, 256, 0, stream>>>(CTX, PROJW, proj_b, X, 192);

    ln_h<<<NTOK / 4, 256, 0, stream>>>(X, hidden, ln1_g, ln1_b, HRES, HPK);

    pack_w<<<36, 256, 0, stream>>>(fc1_w, FC1W, 192, 384);
    pack_w<<<36, 256, 0, stream>>>(fc2_w, FC2W, 384, 192);

    gemm_mfma<192, 1, true, EPI_GELU, 48><<<1152, 256, 0, stream>>>(HPK, FC1W, fc1_b, MID, 384);
    gemm_mfma<384, 3, false, EPI_NONE, 1><<<1152, 256, 0, stream>>>(MID, FC2W, fc2_b, Y, 192);

    ln_out<<<NTOK / 4, 256, 0, stream>>>(Y, HRES, ln2_g, ln2_b, OUT);
}